// Round 1
// baseline (278.676 us; speedup 1.0000x reference)
//
#include <hip/hip_runtime.h>
#include <math.h>

typedef float floatx4 __attribute__((ext_vector_type(4)));

#define NAG   32
#define NOBS  16
#define NN    80
#define KK    5
#define EKNN  400   // NN*KK
#define ED    416   // EKNN + NOBS
#define HID   128

__device__ __forceinline__ int swz(int n, int c) { return c ^ (n & 7); }

// ---- dual node-linear: xl = h@Wl + bl, xr = h@Wr + br  (output F = 128) ----
template<int F_IN>
__device__ __forceinline__ void node_linear(const float* hin,
    const float* __restrict__ Wl, const float* __restrict__ bl,
    const float* __restrict__ Wr, const float* __restrict__ br,
    float* xl, float* xr, int t)
{
    const int tj = t & 15;   // fo block: fo = tj*8 + [0..7]
    const int ti = t >> 4;   // node base: n = ti + 16*a, a in 0..4
    float accl[5][8], accr[5][8];
#pragma unroll
    for (int a = 0; a < 5; a++)
#pragma unroll
        for (int b = 0; b < 8; b++) { accl[a][b] = 0.f; accr[a][b] = 0.f; }

    if constexpr (F_IN == 5) {
#pragma unroll
        for (int fi = 0; fi < 5; ++fi) {
            float hv[5];
#pragma unroll
            for (int a = 0; a < 5; a++) hv[a] = hin[(ti + 16*a)*5 + fi];
            floatx4 wl0 = *(const floatx4*)(Wl + fi*HID + tj*8);
            floatx4 wl1 = *(const floatx4*)(Wl + fi*HID + tj*8 + 4);
            floatx4 wr0 = *(const floatx4*)(Wr + fi*HID + tj*8);
            floatx4 wr1 = *(const floatx4*)(Wr + fi*HID + tj*8 + 4);
#pragma unroll
            for (int a = 0; a < 5; a++) {
#pragma unroll
                for (int c = 0; c < 4; c++) {
                    accl[a][c]   += hv[a]*wl0[c];
                    accl[a][4+c] += hv[a]*wl1[c];
                    accr[a][c]   += hv[a]*wr0[c];
                    accr[a][4+c] += hv[a]*wr1[c];
                }
            }
        }
    } else {
#pragma unroll 2
        for (int fi = 0; fi < F_IN; fi += 4) {
            floatx4 hv4[5];
#pragma unroll
            for (int a = 0; a < 5; a++) {
                int n = ti + 16*a;
                hv4[a] = ((const floatx4*)hin)[n*32 + swz(n, fi >> 2)];
            }
#pragma unroll
            for (int u = 0; u < 4; u++) {
                floatx4 wl0 = *(const floatx4*)(Wl + (fi+u)*HID + tj*8);
                floatx4 wl1 = *(const floatx4*)(Wl + (fi+u)*HID + tj*8 + 4);
                floatx4 wr0 = *(const floatx4*)(Wr + (fi+u)*HID + tj*8);
                floatx4 wr1 = *(const floatx4*)(Wr + (fi+u)*HID + tj*8 + 4);
#pragma unroll
                for (int a = 0; a < 5; a++) {
                    float hv = hv4[a][u];
#pragma unroll
                    for (int c = 0; c < 4; c++) {
                        accl[a][c]   += hv*wl0[c];
                        accl[a][4+c] += hv*wl1[c];
                        accr[a][c]   += hv*wr0[c];
                        accr[a][4+c] += hv*wr1[c];
                    }
                }
            }
        }
    }

#pragma unroll
    for (int a = 0; a < 5; a++) {
        int n = ti + 16*a;
#pragma unroll
        for (int b2 = 0; b2 < 2; b2++) {
            int c = tj*2 + b2;   // float4 column 0..31
            floatx4 bl4 = *(const floatx4*)(bl + 4*c);
            floatx4 br4 = *(const floatx4*)(br + 4*c);
            floatx4 vl, vr;
#pragma unroll
            for (int k = 0; k < 4; k++) {
                vl[k] = accl[a][b2*4+k] + bl4[k];
                vr[k] = accr[a][b2*4+k] + br4[k];
            }
            ((floatx4*)xl)[n*32 + swz(n, c)] = vl;
            ((floatx4*)xr)[n*32 + swz(n, c)] = vr;
        }
    }
}

// ---- per-dst softmax over incoming edges (5 knn + optional goal edge) ----
__device__ __forceinline__ void seg_softmax(const float* logitS, const int* gmask,
                                            float* alphaS, int t)
{
    if (t < NN) {
        const int n = t;
        float l[KK];
#pragma unroll
        for (int k = 0; k < KK; k++) l[k] = logitS[n*KK + k];
        float m = l[0];
#pragma unroll
        for (int k = 1; k < KK; k++) m = fmaxf(m, l[k]);
        int ge = -1; float lg = 0.f;
        if (n >= NAG && n < NAG + NOBS && gmask[n - NAG]) {
            ge = EKNN + (n - NAG);
            lg = logitS[ge];
            m = fmaxf(m, lg);
        }
        float s = 0.f, av[KK];
#pragma unroll
        for (int k = 0; k < KK; k++) { av[k] = expf(l[k] - m); s += av[k]; }
        float ag = 0.f;
        if (ge >= 0) { ag = expf(lg - m); s += ag; }
        float inv = 1.f / s;
#pragma unroll
        for (int k = 0; k < KK; k++) alphaS[n*KK + k] = av[k]*inv;
        if (ge >= 0) alphaS[ge] = ag*inv;
    }
}

// ---- out[n][f] = bias[f] + sum_e alpha_e * xl[src_e][f]  (F = 128) ----
__device__ __forceinline__ void aggregate(const float* xlS, const float* alphaS,
                                          const int* nbr, const int* gmask,
                                          const float* __restrict__ bias,
                                          float* hout, bool relu_out, int t)
{
    for (int idx = t; idx < NN*32; idx += 256) {
        int n = idx >> 5;
        int c = idx & 31;
        floatx4 acc = *(const floatx4*)(bias + 4*c);
#pragma unroll
        for (int k = 0; k < KK; k++) {
            float a = alphaS[n*KK + k];
            int s = nbr[n*KK + k];
            floatx4 v = ((const floatx4*)xlS)[s*32 + swz(s, c)];
#pragma unroll
            for (int q = 0; q < 4; q++) acc[q] += a * v[q];
        }
        if (n >= NAG && n < NAG + NOBS && gmask[n - NAG]) {
            float a = alphaS[EKNN + (n - NAG)];
            int s = n - NAG;
            floatx4 v = ((const floatx4*)xlS)[s*32 + swz(s, c)];
#pragma unroll
            for (int q = 0; q < 4; q++) acc[q] += a * v[q];
        }
        if (relu_out) {
#pragma unroll
            for (int q = 0; q < 4; q++) acc[q] = fmaxf(acc[q], 0.f);
        }
        ((floatx4*)hout)[n*32 + swz(n, c)] = acc;
    }
}

__global__ __launch_bounds__(256, 1) void e3_kernel(
    const float* __restrict__ obst, const float* __restrict__ apos,
    const float* __restrict__ gpos, const float* __restrict__ avel,
    const float* __restrict__ Wl1, const float* __restrict__ bl1,
    const float* __restrict__ Wr1, const float* __restrict__ br1,
    const float* __restrict__ We1, const float* __restrict__ att1, const float* __restrict__ bias1,
    const float* __restrict__ Wl2, const float* __restrict__ bl2,
    const float* __restrict__ Wr2, const float* __restrict__ br2,
    const float* __restrict__ We2, const float* __restrict__ att2, const float* __restrict__ bias2,
    const float* __restrict__ Wl3, const float* __restrict__ bl3,
    const float* __restrict__ Wr3, const float* __restrict__ br3,
    const float* __restrict__ We3, const float* __restrict__ att3, const float* __restrict__ bias3,
    float* __restrict__ out)
{
    __shared__ float pos0[NN], pos1[NN], vel0[NN], vel1[NN], rad[NN];
    __shared__ float xfeat[NN*5];
    __shared__ int   nbr[NN*KK];
    __shared__ int   gmask[NOBS];
    __shared__ float eaS[ED*5];
    __shared__ float logitS[ED];
    __shared__ float alphaS[ED];
    __shared__ __align__(16) float hS[NN*HID];
    __shared__ __align__(16) float xlS[NN*HID];
    __shared__ __align__(16) float xrS[NN*HID];
    __shared__ __align__(16) float weS[5*HID];
    __shared__ __align__(16) float attS[HID];
    __shared__ float xl3S[NN], xr3S[NN];
    __shared__ float resS;

    const int g = blockIdx.x;
    const int t = threadIdx.x;

    // ---------- phase A: load graph ----------
    if (t < NN) {
        int n = t;
        float px, py, vx = 0.f, vy = 0.f, r;
        if (n < NAG) {
            px = apos[(g*NAG + n)*2 + 0]; py = apos[(g*NAG + n)*2 + 1];
            vx = avel[(g*NAG + n)*2 + 0]; vy = avel[(g*NAG + n)*2 + 1];
            r = 0.05f;
        } else if (n < 2*NAG) {
            int m = n - NAG;
            px = gpos[(g*NAG + m)*2 + 0]; py = gpos[(g*NAG + m)*2 + 1];
            r = 0.f;
        } else {
            int m = n - 2*NAG;
            px = obst[(g*NOBS + m)*2 + 0]; py = obst[(g*NOBS + m)*2 + 1];
            r = 0.1f;
        }
        pos0[n] = px; pos1[n] = py; vel0[n] = vx; vel1[n] = vy; rad[n] = r;
        xfeat[n*5 + 0] = (n < NAG) ? 1.f : 0.f;
        xfeat[n*5 + 1] = (n >= NAG && n < 2*NAG) ? 1.f : 0.f;
        xfeat[n*5 + 2] = (n >= 2*NAG) ? 1.f : 0.f;
        xfeat[n*5 + 3] = (n < NAG) ? sqrtf(__fadd_rn(__fmul_rn(vx,vx), __fmul_rn(vy,vy))) : 0.f;
        xfeat[n*5 + 4] = r;
    }
    __syncthreads();

    // ---------- phase B: kNN top-5 (ascending d2, stable on ties == top_k) ----------
    if (t < NN) {
        const int i = t;
        float bd[KK]; int bi[KK];
#pragma unroll
        for (int k = 0; k < KK; k++) { bd[k] = 3.4e38f; bi[k] = -1; }
        const float pix = pos0[i], piy = pos1[i];
        for (int j = 0; j < NN; j++) {
            float dx = __fsub_rn(pix, pos0[j]);
            float dy = __fsub_rn(piy, pos1[j]);
            float d2 = __fadd_rn(__fmul_rn(dx,dx), __fmul_rn(dy,dy));
            if (d2 < bd[KK-1]) {
                int p = KK - 1;
                while (p > 0 && d2 < bd[p-1]) { bd[p] = bd[p-1]; bi[p] = bi[p-1]; p--; }
                bd[p] = d2; bi[p] = j;
            }
        }
#pragma unroll
        for (int k = 0; k < KK; k++) nbr[i*KK + k] = bi[k];
    }
    __syncthreads();

    // goal-edge dedup mask: ag edge (j -> 32+j) duplicates a knn edge iff nbr[32+j] contains j
    if (t < NOBS) {
        int j = t, dup = 0;
#pragma unroll
        for (int k = 0; k < KK; k++) dup |= (nbr[(NAG + j)*KK + k] == j);
        gmask[j] = !dup;
    }
    __syncthreads();

    // ---------- phase C: edge attributes ----------
    for (int e = t; e < ED; e += 256) {
        int src, dst;
        if (e < EKNN) { dst = e / KK; src = nbr[e]; }
        else          { src = e - EKNN; dst = src + NAG; }
        float pdx = pos0[src] - pos0[dst];
        float pdy = pos1[src] - pos1[dst];
        float dist = sqrtf(pdx*pdx + pdy*pdy);
        float inv = 1.f / fmaxf(dist, 1e-6f);
        float pnx = pdx * inv, pny = pdy * inv;
        float rvx = vel0[src] - vel0[dst];
        float rvy = vel1[src] - vel1[dst];
        eaS[e*5 + 0] = (src < NAG && dst == src + NAG) ? 1.f : 0.f;
        eaS[e*5 + 1] = dist;
        eaS[e*5 + 2] = dist - (rad[src] + rad[dst]);
        eaS[e*5 + 3] = rvx*pnx + rvy*pny;
        eaS[e*5 + 4] = rvx*pny - rvy*pnx;
    }
    __syncthreads();

    // ================= layers 1 & 2 (F_out = 128) =================
    const float* WlA[2]   = { Wl1, Wl2 };
    const float* blA[2]   = { bl1, bl2 };
    const float* WrA[2]   = { Wr1, Wr2 };
    const float* brA[2]   = { br1, br2 };
    const float* WeA[2]   = { We1, We2 };
    const float* attA[2]  = { att1, att2 };
    const float* biasA[2] = { bias1, bias2 };

    for (int L = 0; L < 2; L++) {
        // stage We/att in LDS
        for (int i = t; i < 5*HID; i += 256) weS[i] = WeA[L][i];
        for (int i = t; i < HID;  i += 256) attS[i] = attA[L][i];

        if (L == 0) node_linear<5>(xfeat, WlA[0], blA[0], WrA[0], brA[0], xlS, xrS, t);
        else        node_linear<HID>(hS,  WlA[1], blA[1], WrA[1], brA[1], xlS, xrS, t);
        __syncthreads();

        // edge logits
        for (int e = t; e < ED; e += 256) {
            int src, dst;
            if (e < EKNN) { dst = e / KK; src = nbr[e]; }
            else { src = e - EKNN; dst = src + NAG; if (!gmask[src]) continue; }
            float e0 = eaS[e*5+0], e1 = eaS[e*5+1], e2 = eaS[e*5+2],
                  e3 = eaS[e*5+3], e4 = eaS[e*5+4];
            float acc = 0.f;
#pragma unroll 4
            for (int q = 0; q < 32; q++) {
                floatx4 vl = ((const floatx4*)xlS)[src*32 + swz(src, q)];
                floatx4 vr = ((const floatx4*)xrS)[dst*32 + swz(dst, q)];
                floatx4 w0 = ((const floatx4*)weS)[0*32 + q];
                floatx4 w1 = ((const floatx4*)weS)[1*32 + q];
                floatx4 w2 = ((const floatx4*)weS)[2*32 + q];
                floatx4 w3 = ((const floatx4*)weS)[3*32 + q];
                floatx4 w4 = ((const floatx4*)weS)[4*32 + q];
                floatx4 at = ((const floatx4*)attS)[q];
#pragma unroll
                for (int c = 0; c < 4; c++) {
                    float s = vl[c] + vr[c] + e0*w0[c] + e1*w1[c] + e2*w2[c] + e3*w3[c] + e4*w4[c];
                    s = fmaxf(s, 0.2f*s);   // leaky_relu(s, 0.2)
                    acc += s * at[c];
                }
            }
            logitS[e] = acc;
        }
        __syncthreads();

        seg_softmax(logitS, gmask, alphaS, t);
        __syncthreads();

        aggregate(xlS, alphaS, nbr, gmask, biasA[L], hS, true, t);
        __syncthreads();
    }

    // ================= layer 3 (F_out = 1) =================
    if (t < NN) {
        int n = t;
        float al = 0.f, ar = 0.f;
#pragma unroll 8
        for (int q = 0; q < 32; q++) {
            floatx4 hv = ((const floatx4*)hS)[n*32 + swz(n, q)];
            floatx4 wl = *(const floatx4*)(Wl3 + 4*q);
            floatx4 wr = *(const floatx4*)(Wr3 + 4*q);
            al += hv[0]*wl[0] + hv[1]*wl[1] + hv[2]*wl[2] + hv[3]*wl[3];
            ar += hv[0]*wr[0] + hv[1]*wr[1] + hv[2]*wr[2] + hv[3]*wr[3];
        }
        xl3S[n] = al + bl3[0];
        xr3S[n] = ar + br3[0];
    }
    __syncthreads();

    {
        float w0 = We3[0], w1 = We3[1], w2 = We3[2], w3 = We3[3], w4 = We3[4];
        float a0 = att3[0];
        for (int e = t; e < ED; e += 256) {
            int src, dst;
            if (e < EKNN) { dst = e / KK; src = nbr[e]; }
            else { src = e - EKNN; dst = src + NAG; if (!gmask[src]) continue; }
            float s = xl3S[src] + xr3S[dst]
                    + eaS[e*5+0]*w0 + eaS[e*5+1]*w1 + eaS[e*5+2]*w2
                    + eaS[e*5+3]*w3 + eaS[e*5+4]*w4;
            s = fmaxf(s, 0.2f*s);
            logitS[e] = s * a0;
        }
    }
    __syncthreads();

    seg_softmax(logitS, gmask, alphaS, t);
    __syncthreads();

    // final: sum over agent nodes of (bias3 + sum_e alpha*xl3[src]); broadcast to 32 outputs
    float v = 0.f;
    if (t < NAG) {
        v = bias3[0];
#pragma unroll
        for (int k = 0; k < KK; k++) v += alphaS[t*KK + k] * xl3S[nbr[t*KK + k]];
    }
    if (t < 64) {
#pragma unroll
        for (int o = 32; o > 0; o >>= 1) v += __shfl_xor(v, o);
        if (t == 0) resS = v;
    }
    __syncthreads();
    if (t < NAG) out[g*NAG + t] = resS;
}

extern "C" void kernel_launch(void* const* d_in, const int* in_sizes, int n_in,
                              void* d_out, int out_size, void* d_ws, size_t ws_size,
                              hipStream_t stream)
{
    const float* obst = (const float*)d_in[0];
    const float* apos = (const float*)d_in[1];
    const float* gpos = (const float*)d_in[2];
    const float* avel = (const float*)d_in[3];
    const int B = in_sizes[1] / (NAG * 2);

    e3_kernel<<<B, 256, 0, stream>>>(
        obst, apos, gpos, avel,
        (const float*)d_in[4],  (const float*)d_in[5],  (const float*)d_in[6],
        (const float*)d_in[7],  (const float*)d_in[8],  (const float*)d_in[9],
        (const float*)d_in[10],
        (const float*)d_in[11], (const float*)d_in[12], (const float*)d_in[13],
        (const float*)d_in[14], (const float*)d_in[15], (const float*)d_in[16],
        (const float*)d_in[17],
        (const float*)d_in[18], (const float*)d_in[19], (const float*)d_in[20],
        (const float*)d_in[21], (const float*)d_in[22], (const float*)d_in[23],
        (const float*)d_in[24],
        (float*)d_out);
}

// Round 2
// 278.568 us; speedup vs baseline: 1.0004x; 1.0004x over previous
//
#include <hip/hip_runtime.h>
#include <math.h>

typedef float floatx4 __attribute__((ext_vector_type(4)));

#define NAG   32
#define NOBS  16
#define NN    80
#define KK    5
#define EKNN  400   // NN*KK
#define ED    416   // EKNN + NOBS
#define HID   128

__device__ __forceinline__ int swz(int n, int c) { return c ^ (n & 7); }

// ---- dual node-linear: xl = h@Wl + bl, xr = h@Wr + br  (output F = 128) ----
template<int F_IN>
__device__ __forceinline__ void node_linear(const float* hin,
    const float* __restrict__ Wl, const float* __restrict__ bl,
    const float* __restrict__ Wr, const float* __restrict__ br,
    float* xl, float* xr, int t)
{
    const int tj = t & 15;   // fo block: fo = tj*8 + [0..7]
    const int ti = t >> 4;   // node base: n = ti + 16*a, a in 0..4
    float accl[5][8], accr[5][8];
#pragma unroll
    for (int a = 0; a < 5; a++)
#pragma unroll
        for (int b = 0; b < 8; b++) { accl[a][b] = 0.f; accr[a][b] = 0.f; }

    if constexpr (F_IN == 5) {
#pragma unroll
        for (int fi = 0; fi < 5; ++fi) {
            float hv[5];
#pragma unroll
            for (int a = 0; a < 5; a++) hv[a] = hin[(ti + 16*a)*5 + fi];
            floatx4 wl0 = *(const floatx4*)(Wl + fi*HID + tj*8);
            floatx4 wl1 = *(const floatx4*)(Wl + fi*HID + tj*8 + 4);
            floatx4 wr0 = *(const floatx4*)(Wr + fi*HID + tj*8);
            floatx4 wr1 = *(const floatx4*)(Wr + fi*HID + tj*8 + 4);
#pragma unroll
            for (int a = 0; a < 5; a++) {
#pragma unroll
                for (int c = 0; c < 4; c++) {
                    accl[a][c]   += hv[a]*wl0[c];
                    accl[a][4+c] += hv[a]*wl1[c];
                    accr[a][c]   += hv[a]*wr0[c];
                    accr[a][4+c] += hv[a]*wr1[c];
                }
            }
        }
    } else {
#pragma unroll 2
        for (int fi = 0; fi < F_IN; fi += 4) {
            floatx4 hv4[5];
#pragma unroll
            for (int a = 0; a < 5; a++) {
                int n = ti + 16*a;
                hv4[a] = ((const floatx4*)hin)[n*32 + swz(n, fi >> 2)];
            }
#pragma unroll
            for (int u = 0; u < 4; u++) {
                floatx4 wl0 = *(const floatx4*)(Wl + (fi+u)*HID + tj*8);
                floatx4 wl1 = *(const floatx4*)(Wl + (fi+u)*HID + tj*8 + 4);
                floatx4 wr0 = *(const floatx4*)(Wr + (fi+u)*HID + tj*8);
                floatx4 wr1 = *(const floatx4*)(Wr + (fi+u)*HID + tj*8 + 4);
#pragma unroll
                for (int a = 0; a < 5; a++) {
                    float hv = hv4[a][u];
#pragma unroll
                    for (int c = 0; c < 4; c++) {
                        accl[a][c]   += hv*wl0[c];
                        accl[a][4+c] += hv*wl1[c];
                        accr[a][c]   += hv*wr0[c];
                        accr[a][4+c] += hv*wr1[c];
                    }
                }
            }
        }
    }

#pragma unroll
    for (int a = 0; a < 5; a++) {
        int n = ti + 16*a;
#pragma unroll
        for (int b2 = 0; b2 < 2; b2++) {
            int c = tj*2 + b2;   // float4 column 0..31
            floatx4 bl4 = *(const floatx4*)(bl + 4*c);
            floatx4 br4 = *(const floatx4*)(br + 4*c);
            floatx4 vl, vr;
#pragma unroll
            for (int k = 0; k < 4; k++) {
                vl[k] = accl[a][b2*4+k] + bl4[k];
                vr[k] = accr[a][b2*4+k] + br4[k];
            }
            ((floatx4*)xl)[n*32 + swz(n, c)] = vl;
            ((floatx4*)xr)[n*32 + swz(n, c)] = vr;
        }
    }
}

// ---- per-dst softmax over incoming edges (5 knn + optional goal edge) ----
__device__ __forceinline__ void seg_softmax(const float* logitS, const int* gmask,
                                            float* alphaS, int t)
{
    if (t < NN) {
        const int n = t;
        float l[KK];
#pragma unroll
        for (int k = 0; k < KK; k++) l[k] = logitS[n*KK + k];
        float m = l[0];
#pragma unroll
        for (int k = 1; k < KK; k++) m = fmaxf(m, l[k]);
        int ge = -1; float lg = 0.f;
        if (n >= NAG && n < NAG + NOBS && gmask[n - NAG]) {
            ge = EKNN + (n - NAG);
            lg = logitS[ge];
            m = fmaxf(m, lg);
        }
        float s = 0.f, av[KK];
#pragma unroll
        for (int k = 0; k < KK; k++) { av[k] = expf(l[k] - m); s += av[k]; }
        float ag = 0.f;
        if (ge >= 0) { ag = expf(lg - m); s += ag; }
        float inv = 1.f / s;
#pragma unroll
        for (int k = 0; k < KK; k++) alphaS[n*KK + k] = av[k]*inv;
        if (ge >= 0) alphaS[ge] = ag*inv;
    }
}

// ---- out[n][f] = bias[f] + sum_e alpha_e * xl[src_e][f]  (F = 128) ----
__device__ __forceinline__ void aggregate(const float* xlS, const float* alphaS,
                                          const int* nbr, const int* gmask,
                                          const float* __restrict__ bias,
                                          float* hout, bool relu_out, int t)
{
    for (int idx = t; idx < NN*32; idx += 256) {
        int n = idx >> 5;
        int c = idx & 31;
        floatx4 acc = *(const floatx4*)(bias + 4*c);
#pragma unroll
        for (int k = 0; k < KK; k++) {
            float a = alphaS[n*KK + k];
            int s = nbr[n*KK + k];
            floatx4 v = ((const floatx4*)xlS)[s*32 + swz(s, c)];
#pragma unroll
            for (int q = 0; q < 4; q++) acc[q] += a * v[q];
        }
        if (n >= NAG && n < NAG + NOBS && gmask[n - NAG]) {
            float a = alphaS[EKNN + (n - NAG)];
            int s = n - NAG;
            floatx4 v = ((const floatx4*)xlS)[s*32 + swz(s, c)];
#pragma unroll
            for (int q = 0; q < 4; q++) acc[q] += a * v[q];
        }
        if (relu_out) {
#pragma unroll
            for (int q = 0; q < 4; q++) acc[q] = fmaxf(acc[q], 0.f);
        }
        ((floatx4*)hout)[n*32 + swz(n, c)] = acc;
    }
}

__global__ __launch_bounds__(256, 1) void e3_kernel(
    const float* __restrict__ obst, const float* __restrict__ apos,
    const float* __restrict__ gpos, const float* __restrict__ avel,
    const float* __restrict__ Wl1, const float* __restrict__ bl1,
    const float* __restrict__ Wr1, const float* __restrict__ br1,
    const float* __restrict__ We1, const float* __restrict__ att1, const float* __restrict__ bias1,
    const float* __restrict__ Wl2, const float* __restrict__ bl2,
    const float* __restrict__ Wr2, const float* __restrict__ br2,
    const float* __restrict__ We2, const float* __restrict__ att2, const float* __restrict__ bias2,
    const float* __restrict__ Wl3, const float* __restrict__ bl3,
    const float* __restrict__ Wr3, const float* __restrict__ br3,
    const float* __restrict__ We3, const float* __restrict__ att3, const float* __restrict__ bias3,
    float* __restrict__ out)
{
    __shared__ float pos0[NN], pos1[NN], vel0[NN], vel1[NN], rad[NN];
    __shared__ float xfeat[NN*5];
    __shared__ int   nbr[NN*KK];
    __shared__ int   gmask[NOBS];
    __shared__ float eaS[ED*5];
    __shared__ float logitS[ED];
    __shared__ float alphaS[ED];
    __shared__ __align__(16) float hS[NN*HID];
    __shared__ __align__(16) float xlS[NN*HID];
    __shared__ __align__(16) float xrS[NN*HID];
    __shared__ __align__(16) float weS[5*HID];
    __shared__ __align__(16) float attS[HID];
    __shared__ float xl3S[NN], xr3S[NN];
    __shared__ float resS;

    const int g = blockIdx.x;
    const int t = threadIdx.x;

    // ---------- phase A: load graph ----------
    if (t < NN) {
        int n = t;
        float px, py, vx = 0.f, vy = 0.f, r;
        if (n < NAG) {
            px = apos[(g*NAG + n)*2 + 0]; py = apos[(g*NAG + n)*2 + 1];
            vx = avel[(g*NAG + n)*2 + 0]; vy = avel[(g*NAG + n)*2 + 1];
            r = 0.05f;
        } else if (n < 2*NAG) {
            int m = n - NAG;
            px = gpos[(g*NAG + m)*2 + 0]; py = gpos[(g*NAG + m)*2 + 1];
            r = 0.f;
        } else {
            int m = n - 2*NAG;
            px = obst[(g*NOBS + m)*2 + 0]; py = obst[(g*NOBS + m)*2 + 1];
            r = 0.1f;
        }
        pos0[n] = px; pos1[n] = py; vel0[n] = vx; vel1[n] = vy; rad[n] = r;
        xfeat[n*5 + 0] = (n < NAG) ? 1.f : 0.f;
        xfeat[n*5 + 1] = (n >= NAG && n < 2*NAG) ? 1.f : 0.f;
        xfeat[n*5 + 2] = (n >= 2*NAG) ? 1.f : 0.f;
        xfeat[n*5 + 3] = (n < NAG) ? sqrtf(__fadd_rn(__fmul_rn(vx,vx), __fmul_rn(vy,vy))) : 0.f;
        xfeat[n*5 + 4] = r;
    }
    __syncthreads();

    // ---------- phase B: kNN top-5 (ascending d2, stable on ties == top_k) ----------
    if (t < NN) {
        const int i = t;
        float bd[KK]; int bi[KK];
#pragma unroll
        for (int k = 0; k < KK; k++) { bd[k] = 3.4e38f; bi[k] = -1; }
        const float pix = pos0[i], piy = pos1[i];
        for (int j = 0; j < NN; j++) {
            float dx = __fsub_rn(pix, pos0[j]);
            float dy = __fsub_rn(piy, pos1[j]);
            float d2 = __fadd_rn(__fmul_rn(dx,dx), __fmul_rn(dy,dy));
            if (d2 < bd[KK-1]) {
                int p = KK - 1;
                while (p > 0 && d2 < bd[p-1]) { bd[p] = bd[p-1]; bi[p] = bi[p-1]; p--; }
                bd[p] = d2; bi[p] = j;
            }
        }
#pragma unroll
        for (int k = 0; k < KK; k++) nbr[i*KK + k] = bi[k];
    }
    __syncthreads();

    // goal-edge dedup mask: ag edge (j -> 32+j) duplicates a knn edge iff nbr[32+j] contains j
    if (t < NOBS) {
        int j = t, dup = 0;
#pragma unroll
        for (int k = 0; k < KK; k++) dup |= (nbr[(NAG + j)*KK + k] == j);
        gmask[j] = !dup;
    }
    __syncthreads();

    // ---------- phase C: edge attributes ----------
    for (int e = t; e < ED; e += 256) {
        int src, dst;
        if (e < EKNN) { dst = e / KK; src = nbr[e]; }
        else          { src = e - EKNN; dst = src + NAG; }
        float pdx = pos0[src] - pos0[dst];
        float pdy = pos1[src] - pos1[dst];
        float dist = sqrtf(pdx*pdx + pdy*pdy);
        float inv = 1.f / fmaxf(dist, 1e-6f);
        float pnx = pdx * inv, pny = pdy * inv;
        float rvx = vel0[src] - vel0[dst];
        float rvy = vel1[src] - vel1[dst];
        eaS[e*5 + 0] = (src < NAG && dst == src + NAG) ? 1.f : 0.f;
        eaS[e*5 + 1] = dist;
        eaS[e*5 + 2] = dist - (rad[src] + rad[dst]);
        eaS[e*5 + 3] = rvx*pnx + rvy*pny;
        eaS[e*5 + 4] = rvx*pny - rvy*pnx;
    }
    __syncthreads();

    // ================= layers 1 & 2 (F_out = 128) =================
    const float* WlA[2]   = { Wl1, Wl2 };
    const float* blA[2]   = { bl1, bl2 };
    const float* WrA[2]   = { Wr1, Wr2 };
    const float* brA[2]   = { br1, br2 };
    const float* WeA[2]   = { We1, We2 };
    const float* attA[2]  = { att1, att2 };
    const float* biasA[2] = { bias1, bias2 };

    for (int L = 0; L < 2; L++) {
        // stage We/att in LDS
        for (int i = t; i < 5*HID; i += 256) weS[i] = WeA[L][i];
        for (int i = t; i < HID;  i += 256) attS[i] = attA[L][i];

        if (L == 0) node_linear<5>(xfeat, WlA[0], blA[0], WrA[0], brA[0], xlS, xrS, t);
        else        node_linear<HID>(hS,  WlA[1], blA[1], WrA[1], brA[1], xlS, xrS, t);
        __syncthreads();

        // edge logits
        for (int e = t; e < ED; e += 256) {
            int src, dst;
            if (e < EKNN) { dst = e / KK; src = nbr[e]; }
            else { src = e - EKNN; dst = src + NAG; if (!gmask[src]) continue; }
            float e0 = eaS[e*5+0], e1 = eaS[e*5+1], e2 = eaS[e*5+2],
                  e3 = eaS[e*5+3], e4 = eaS[e*5+4];
            float acc = 0.f;
#pragma unroll 4
            for (int q = 0; q < 32; q++) {
                floatx4 vl = ((const floatx4*)xlS)[src*32 + swz(src, q)];
                floatx4 vr = ((const floatx4*)xrS)[dst*32 + swz(dst, q)];
                floatx4 w0 = ((const floatx4*)weS)[0*32 + q];
                floatx4 w1 = ((const floatx4*)weS)[1*32 + q];
                floatx4 w2 = ((const floatx4*)weS)[2*32 + q];
                floatx4 w3 = ((const floatx4*)weS)[3*32 + q];
                floatx4 w4 = ((const floatx4*)weS)[4*32 + q];
                floatx4 at = ((const floatx4*)attS)[q];
#pragma unroll
                for (int c = 0; c < 4; c++) {
                    float s = vl[c] + vr[c] + e0*w0[c] + e1*w1[c] + e2*w2[c] + e3*w3[c] + e4*w4[c];
                    s = fmaxf(s, 0.2f*s);   // leaky_relu(s, 0.2)
                    acc += s * at[c];
                }
            }
            logitS[e] = acc;
        }
        __syncthreads();

        seg_softmax(logitS, gmask, alphaS, t);
        __syncthreads();

        aggregate(xlS, alphaS, nbr, gmask, biasA[L], hS, true, t);
        __syncthreads();
    }

    // ================= layer 3 (F_out = 1) =================
    if (t < NN) {
        int n = t;
        float al = 0.f, ar = 0.f;
#pragma unroll 8
        for (int q = 0; q < 32; q++) {
            floatx4 hv = ((const floatx4*)hS)[n*32 + swz(n, q)];
            floatx4 wl = *(const floatx4*)(Wl3 + 4*q);
            floatx4 wr = *(const floatx4*)(Wr3 + 4*q);
            al += hv[0]*wl[0] + hv[1]*wl[1] + hv[2]*wl[2] + hv[3]*wl[3];
            ar += hv[0]*wr[0] + hv[1]*wr[1] + hv[2]*wr[2] + hv[3]*wr[3];
        }
        xl3S[n] = al + bl3[0];
        xr3S[n] = ar + br3[0];
    }
    __syncthreads();

    {
        float w0 = We3[0], w1 = We3[1], w2 = We3[2], w3 = We3[3], w4 = We3[4];
        float a0 = att3[0];
        for (int e = t; e < ED; e += 256) {
            int src, dst;
            if (e < EKNN) { dst = e / KK; src = nbr[e]; }
            else { src = e - EKNN; dst = src + NAG; if (!gmask[src]) continue; }
            float s = xl3S[src] + xr3S[dst]
                    + eaS[e*5+0]*w0 + eaS[e*5+1]*w1 + eaS[e*5+2]*w2
                    + eaS[e*5+3]*w3 + eaS[e*5+4]*w4;
            s = fmaxf(s, 0.2f*s);
            logitS[e] = s * a0;
        }
    }
    __syncthreads();

    seg_softmax(logitS, gmask, alphaS, t);
    __syncthreads();

    // final: sum over agent nodes of (bias3 + sum_e alpha*xl3[src]); broadcast to 32 outputs
    float v = 0.f;
    if (t < NAG) {
        v = bias3[0];
#pragma unroll
        for (int k = 0; k < KK; k++) v += alphaS[t*KK + k] * xl3S[nbr[t*KK + k]];
    }
    if (t < 64) {
#pragma unroll
        for (int o = 32; o > 0; o >>= 1) v += __shfl_xor(v, o);
        if (t == 0) resS = v;
    }
    __syncthreads();
    if (t < NAG) out[g*NAG + t] = resS;
}

extern "C" void kernel_launch(void* const* d_in, const int* in_sizes, int n_in,
                              void* d_out, int out_size, void* d_ws, size_t ws_size,
                              hipStream_t stream)
{
    const float* obst = (const float*)d_in[0];
    const float* apos = (const float*)d_in[1];
    const float* gpos = (const float*)d_in[2];
    const float* avel = (const float*)d_in[3];
    const int B = in_sizes[1] / (NAG * 2);

    e3_kernel<<<B, 256, 0, stream>>>(
        obst, apos, gpos, avel,
        (const float*)d_in[4],  (const float*)d_in[5],  (const float*)d_in[6],
        (const float*)d_in[7],  (const float*)d_in[8],  (const float*)d_in[9],
        (const float*)d_in[10],
        (const float*)d_in[11], (const float*)d_in[12], (const float*)d_in[13],
        (const float*)d_in[14], (const float*)d_in[15], (const float*)d_in[16],
        (const float*)d_in[17],
        (const float*)d_in[18], (const float*)d_in[19], (const float*)d_in[20],
        (const float*)d_in[21], (const float*)d_in[22], (const float*)d_in[23],
        (const float*)d_in[24],
        (float*)d_out);
}

// Round 3
// 278.510 us; speedup vs baseline: 1.0006x; 1.0002x over previous
//
#include <hip/hip_runtime.h>
#include <math.h>

typedef float floatx4 __attribute__((ext_vector_type(4)));

#define NAG   32
#define NOBS  16
#define NN    80
#define KK    5
#define EKNN  400   // NN*KK
#define ED    416   // EKNN + NOBS
#define HID   128

__device__ __forceinline__ int swz(int n, int c) { return c ^ (n & 7); }

// ---- dual node-linear: xl = h@Wl + bl, xr = h@Wr + br  (output F = 128) ----
template<int F_IN>
__device__ __forceinline__ void node_linear(const float* hin,
    const float* __restrict__ Wl, const float* __restrict__ bl,
    const float* __restrict__ Wr, const float* __restrict__ br,
    float* xl, float* xr, int t)
{
    const int tj = t & 15;   // fo block: fo = tj*8 + [0..7]
    const int ti = t >> 4;   // node base: n = ti + 16*a, a in 0..4
    float accl[5][8], accr[5][8];
#pragma unroll
    for (int a = 0; a < 5; a++)
#pragma unroll
        for (int b = 0; b < 8; b++) { accl[a][b] = 0.f; accr[a][b] = 0.f; }

    if constexpr (F_IN == 5) {
#pragma unroll
        for (int fi = 0; fi < 5; ++fi) {
            float hv[5];
#pragma unroll
            for (int a = 0; a < 5; a++) hv[a] = hin[(ti + 16*a)*5 + fi];
            floatx4 wl0 = *(const floatx4*)(Wl + fi*HID + tj*8);
            floatx4 wl1 = *(const floatx4*)(Wl + fi*HID + tj*8 + 4);
            floatx4 wr0 = *(const floatx4*)(Wr + fi*HID + tj*8);
            floatx4 wr1 = *(const floatx4*)(Wr + fi*HID + tj*8 + 4);
#pragma unroll
            for (int a = 0; a < 5; a++) {
#pragma unroll
                for (int c = 0; c < 4; c++) {
                    accl[a][c]   += hv[a]*wl0[c];
                    accl[a][4+c] += hv[a]*wl1[c];
                    accr[a][c]   += hv[a]*wr0[c];
                    accr[a][4+c] += hv[a]*wr1[c];
                }
            }
        }
    } else {
#pragma unroll 2
        for (int fi = 0; fi < F_IN; fi += 4) {
            floatx4 hv4[5];
#pragma unroll
            for (int a = 0; a < 5; a++) {
                int n = ti + 16*a;
                hv4[a] = ((const floatx4*)hin)[n*32 + swz(n, fi >> 2)];
            }
#pragma unroll
            for (int u = 0; u < 4; u++) {
                floatx4 wl0 = *(const floatx4*)(Wl + (fi+u)*HID + tj*8);
                floatx4 wl1 = *(const floatx4*)(Wl + (fi+u)*HID + tj*8 + 4);
                floatx4 wr0 = *(const floatx4*)(Wr + (fi+u)*HID + tj*8);
                floatx4 wr1 = *(const floatx4*)(Wr + (fi+u)*HID + tj*8 + 4);
#pragma unroll
                for (int a = 0; a < 5; a++) {
                    float hv = hv4[a][u];
#pragma unroll
                    for (int c = 0; c < 4; c++) {
                        accl[a][c]   += hv*wl0[c];
                        accl[a][4+c] += hv*wl1[c];
                        accr[a][c]   += hv*wr0[c];
                        accr[a][4+c] += hv*wr1[c];
                    }
                }
            }
        }
    }

#pragma unroll
    for (int a = 0; a < 5; a++) {
        int n = ti + 16*a;
#pragma unroll
        for (int b2 = 0; b2 < 2; b2++) {
            int c = tj*2 + b2;   // float4 column 0..31
            floatx4 bl4 = *(const floatx4*)(bl + 4*c);
            floatx4 br4 = *(const floatx4*)(br + 4*c);
            floatx4 vl, vr;
#pragma unroll
            for (int k = 0; k < 4; k++) {
                vl[k] = accl[a][b2*4+k] + bl4[k];
                vr[k] = accr[a][b2*4+k] + br4[k];
            }
            ((floatx4*)xl)[n*32 + swz(n, c)] = vl;
            ((floatx4*)xr)[n*32 + swz(n, c)] = vr;
        }
    }
}

// ---- per-dst softmax over incoming edges (5 knn + optional goal edge) ----
__device__ __forceinline__ void seg_softmax(const float* logitS, const int* gmask,
                                            float* alphaS, int t)
{
    if (t < NN) {
        const int n = t;
        float l[KK];
#pragma unroll
        for (int k = 0; k < KK; k++) l[k] = logitS[n*KK + k];
        float m = l[0];
#pragma unroll
        for (int k = 1; k < KK; k++) m = fmaxf(m, l[k]);
        int ge = -1; float lg = 0.f;
        if (n >= NAG && n < NAG + NOBS && gmask[n - NAG]) {
            ge = EKNN + (n - NAG);
            lg = logitS[ge];
            m = fmaxf(m, lg);
        }
        float s = 0.f, av[KK];
#pragma unroll
        for (int k = 0; k < KK; k++) { av[k] = expf(l[k] - m); s += av[k]; }
        float ag = 0.f;
        if (ge >= 0) { ag = expf(lg - m); s += ag; }
        float inv = 1.f / s;
#pragma unroll
        for (int k = 0; k < KK; k++) alphaS[n*KK + k] = av[k]*inv;
        if (ge >= 0) alphaS[ge] = ag*inv;
    }
}

// ---- out[n][f] = bias[f] + sum_e alpha_e * xl[src_e][f]  (F = 128) ----
__device__ __forceinline__ void aggregate(const float* xlS, const float* alphaS,
                                          const int* nbr, const int* gmask,
                                          const float* __restrict__ bias,
                                          float* hout, bool relu_out, int t)
{
    for (int idx = t; idx < NN*32; idx += 256) {
        int n = idx >> 5;
        int c = idx & 31;
        floatx4 acc = *(const floatx4*)(bias + 4*c);
#pragma unroll
        for (int k = 0; k < KK; k++) {
            float a = alphaS[n*KK + k];
            int s = nbr[n*KK + k];
            floatx4 v = ((const floatx4*)xlS)[s*32 + swz(s, c)];
#pragma unroll
            for (int q = 0; q < 4; q++) acc[q] += a * v[q];
        }
        if (n >= NAG && n < NAG + NOBS && gmask[n - NAG]) {
            float a = alphaS[EKNN + (n - NAG)];
            int s = n - NAG;
            floatx4 v = ((const floatx4*)xlS)[s*32 + swz(s, c)];
#pragma unroll
            for (int q = 0; q < 4; q++) acc[q] += a * v[q];
        }
        if (relu_out) {
#pragma unroll
            for (int q = 0; q < 4; q++) acc[q] = fmaxf(acc[q], 0.f);
        }
        ((floatx4*)hout)[n*32 + swz(n, c)] = acc;
    }
}

__global__ __launch_bounds__(256, 1) void e3_kernel(
    const float* __restrict__ obst, const float* __restrict__ apos,
    const float* __restrict__ gpos, const float* __restrict__ avel,
    const float* __restrict__ Wl1, const float* __restrict__ bl1,
    const float* __restrict__ Wr1, const float* __restrict__ br1,
    const float* __restrict__ We1, const float* __restrict__ att1, const float* __restrict__ bias1,
    const float* __restrict__ Wl2, const float* __restrict__ bl2,
    const float* __restrict__ Wr2, const float* __restrict__ br2,
    const float* __restrict__ We2, const float* __restrict__ att2, const float* __restrict__ bias2,
    const float* __restrict__ Wl3, const float* __restrict__ bl3,
    const float* __restrict__ Wr3, const float* __restrict__ br3,
    const float* __restrict__ We3, const float* __restrict__ att3, const float* __restrict__ bias3,
    float* __restrict__ out)
{
    __shared__ float pos0[NN], pos1[NN], vel0[NN], vel1[NN], rad[NN];
    __shared__ float xfeat[NN*5];
    __shared__ int   nbr[NN*KK];
    __shared__ int   gmask[NOBS];
    __shared__ float eaS[ED*5];
    __shared__ float logitS[ED];
    __shared__ float alphaS[ED];
    __shared__ __align__(16) float hS[NN*HID];
    __shared__ __align__(16) float xlS[NN*HID];
    __shared__ __align__(16) float xrS[NN*HID];
    __shared__ __align__(16) float weS[5*HID];
    __shared__ __align__(16) float attS[HID];
    __shared__ float xl3S[NN], xr3S[NN];
    __shared__ float resS;

    const int g = blockIdx.x;
    const int t = threadIdx.x;

    // ---------- phase A: load graph ----------
    if (t < NN) {
        int n = t;
        float px, py, vx = 0.f, vy = 0.f, r;
        if (n < NAG) {
            px = apos[(g*NAG + n)*2 + 0]; py = apos[(g*NAG + n)*2 + 1];
            vx = avel[(g*NAG + n)*2 + 0]; vy = avel[(g*NAG + n)*2 + 1];
            r = 0.05f;
        } else if (n < 2*NAG) {
            int m = n - NAG;
            px = gpos[(g*NAG + m)*2 + 0]; py = gpos[(g*NAG + m)*2 + 1];
            r = 0.f;
        } else {
            int m = n - 2*NAG;
            px = obst[(g*NOBS + m)*2 + 0]; py = obst[(g*NOBS + m)*2 + 1];
            r = 0.1f;
        }
        pos0[n] = px; pos1[n] = py; vel0[n] = vx; vel1[n] = vy; rad[n] = r;
        xfeat[n*5 + 0] = (n < NAG) ? 1.f : 0.f;
        xfeat[n*5 + 1] = (n >= NAG && n < 2*NAG) ? 1.f : 0.f;
        xfeat[n*5 + 2] = (n >= 2*NAG) ? 1.f : 0.f;
        xfeat[n*5 + 3] = (n < NAG) ? sqrtf(__fadd_rn(__fmul_rn(vx,vx), __fmul_rn(vy,vy))) : 0.f;
        xfeat[n*5 + 4] = r;
    }
    __syncthreads();

    // ---------- phase B: kNN top-5 (ascending d2, stable on ties == top_k) ----------
    if (t < NN) {
        const int i = t;
        float bd[KK]; int bi[KK];
#pragma unroll
        for (int k = 0; k < KK; k++) { bd[k] = 3.4e38f; bi[k] = -1; }
        const float pix = pos0[i], piy = pos1[i];
        for (int j = 0; j < NN; j++) {
            float dx = __fsub_rn(pix, pos0[j]);
            float dy = __fsub_rn(piy, pos1[j]);
            float d2 = __fadd_rn(__fmul_rn(dx,dx), __fmul_rn(dy,dy));
            if (d2 < bd[KK-1]) {
                int p = KK - 1;
                while (p > 0 && d2 < bd[p-1]) { bd[p] = bd[p-1]; bi[p] = bi[p-1]; p--; }
                bd[p] = d2; bi[p] = j;
            }
        }
#pragma unroll
        for (int k = 0; k < KK; k++) nbr[i*KK + k] = bi[k];
    }
    __syncthreads();

    // goal-edge dedup mask: ag edge (j -> 32+j) duplicates a knn edge iff nbr[32+j] contains j
    if (t < NOBS) {
        int j = t, dup = 0;
#pragma unroll
        for (int k = 0; k < KK; k++) dup |= (nbr[(NAG + j)*KK + k] == j);
        gmask[j] = !dup;
    }
    __syncthreads();

    // ---------- phase C: edge attributes ----------
    for (int e = t; e < ED; e += 256) {
        int src, dst;
        if (e < EKNN) { dst = e / KK; src = nbr[e]; }
        else          { src = e - EKNN; dst = src + NAG; }
        float pdx = pos0[src] - pos0[dst];
        float pdy = pos1[src] - pos1[dst];
        float dist = sqrtf(pdx*pdx + pdy*pdy);
        float inv = 1.f / fmaxf(dist, 1e-6f);
        float pnx = pdx * inv, pny = pdy * inv;
        float rvx = vel0[src] - vel0[dst];
        float rvy = vel1[src] - vel1[dst];
        eaS[e*5 + 0] = (src < NAG && dst == src + NAG) ? 1.f : 0.f;
        eaS[e*5 + 1] = dist;
        eaS[e*5 + 2] = dist - (rad[src] + rad[dst]);
        eaS[e*5 + 3] = rvx*pnx + rvy*pny;
        eaS[e*5 + 4] = rvx*pny - rvy*pnx;
    }
    __syncthreads();

    // ================= layers 1 & 2 (F_out = 128) =================
    const float* WlA[2]   = { Wl1, Wl2 };
    const float* blA[2]   = { bl1, bl2 };
    const float* WrA[2]   = { Wr1, Wr2 };
    const float* brA[2]   = { br1, br2 };
    const float* WeA[2]   = { We1, We2 };
    const float* attA[2]  = { att1, att2 };
    const float* biasA[2] = { bias1, bias2 };

    for (int L = 0; L < 2; L++) {
        // stage We/att in LDS
        for (int i = t; i < 5*HID; i += 256) weS[i] = WeA[L][i];
        for (int i = t; i < HID;  i += 256) attS[i] = attA[L][i];

        if (L == 0) node_linear<5>(xfeat, WlA[0], blA[0], WrA[0], brA[0], xlS, xrS, t);
        else        node_linear<HID>(hS,  WlA[1], blA[1], WrA[1], brA[1], xlS, xrS, t);
        __syncthreads();

        // edge logits
        for (int e = t; e < ED; e += 256) {
            int src, dst;
            if (e < EKNN) { dst = e / KK; src = nbr[e]; }
            else { src = e - EKNN; dst = src + NAG; if (!gmask[src]) continue; }
            float e0 = eaS[e*5+0], e1 = eaS[e*5+1], e2 = eaS[e*5+2],
                  e3 = eaS[e*5+3], e4 = eaS[e*5+4];
            float acc = 0.f;
#pragma unroll 4
            for (int q = 0; q < 32; q++) {
                floatx4 vl = ((const floatx4*)xlS)[src*32 + swz(src, q)];
                floatx4 vr = ((const floatx4*)xrS)[dst*32 + swz(dst, q)];
                floatx4 w0 = ((const floatx4*)weS)[0*32 + q];
                floatx4 w1 = ((const floatx4*)weS)[1*32 + q];
                floatx4 w2 = ((const floatx4*)weS)[2*32 + q];
                floatx4 w3 = ((const floatx4*)weS)[3*32 + q];
                floatx4 w4 = ((const floatx4*)weS)[4*32 + q];
                floatx4 at = ((const floatx4*)attS)[q];
#pragma unroll
                for (int c = 0; c < 4; c++) {
                    float s = vl[c] + vr[c] + e0*w0[c] + e1*w1[c] + e2*w2[c] + e3*w3[c] + e4*w4[c];
                    s = fmaxf(s, 0.2f*s);   // leaky_relu(s, 0.2)
                    acc += s * at[c];
                }
            }
            logitS[e] = acc;
        }
        __syncthreads();

        seg_softmax(logitS, gmask, alphaS, t);
        __syncthreads();

        aggregate(xlS, alphaS, nbr, gmask, biasA[L], hS, true, t);
        __syncthreads();
    }

    // ================= layer 3 (F_out = 1) =================
    if (t < NN) {
        int n = t;
        float al = 0.f, ar = 0.f;
#pragma unroll 8
        for (int q = 0; q < 32; q++) {
            floatx4 hv = ((const floatx4*)hS)[n*32 + swz(n, q)];
            floatx4 wl = *(const floatx4*)(Wl3 + 4*q);
            floatx4 wr = *(const floatx4*)(Wr3 + 4*q);
            al += hv[0]*wl[0] + hv[1]*wl[1] + hv[2]*wl[2] + hv[3]*wl[3];
            ar += hv[0]*wr[0] + hv[1]*wr[1] + hv[2]*wr[2] + hv[3]*wr[3];
        }
        xl3S[n] = al + bl3[0];
        xr3S[n] = ar + br3[0];
    }
    __syncthreads();

    {
        float w0 = We3[0], w1 = We3[1], w2 = We3[2], w3 = We3[3], w4 = We3[4];
        float a0 = att3[0];
        for (int e = t; e < ED; e += 256) {
            int src, dst;
            if (e < EKNN) { dst = e / KK; src = nbr[e]; }
            else { src = e - EKNN; dst = src + NAG; if (!gmask[src]) continue; }
            float s = xl3S[src] + xr3S[dst]
                    + eaS[e*5+0]*w0 + eaS[e*5+1]*w1 + eaS[e*5+2]*w2
                    + eaS[e*5+3]*w3 + eaS[e*5+4]*w4;
            s = fmaxf(s, 0.2f*s);
            logitS[e] = s * a0;
        }
    }
    __syncthreads();

    seg_softmax(logitS, gmask, alphaS, t);
    __syncthreads();

    // final: sum over agent nodes of (bias3 + sum_e alpha*xl3[src]); broadcast to 32 outputs
    float v = 0.f;
    if (t < NAG) {
        v = bias3[0];
#pragma unroll
        for (int k = 0; k < KK; k++) v += alphaS[t*KK + k] * xl3S[nbr[t*KK + k]];
    }
    if (t < 64) {
#pragma unroll
        for (int o = 32; o > 0; o >>= 1) v += __shfl_xor(v, o);
        if (t == 0) resS = v;
    }
    __syncthreads();
    if (t < NAG) out[g*NAG + t] = resS;
}

extern "C" void kernel_launch(void* const* d_in, const int* in_sizes, int n_in,
                              void* d_out, int out_size, void* d_ws, size_t ws_size,
                              hipStream_t stream)
{
    const float* obst = (const float*)d_in[0];
    const float* apos = (const float*)d_in[1];
    const float* gpos = (const float*)d_in[2];
    const float* avel = (const float*)d_in[3];
    const int B = in_sizes[1] / (NAG * 2);

    e3_kernel<<<B, 256, 0, stream>>>(
        obst, apos, gpos, avel,
        (const float*)d_in[4],  (const float*)d_in[5],  (const float*)d_in[6],
        (const float*)d_in[7],  (const float*)d_in[8],  (const float*)d_in[9],
        (const float*)d_in[10],
        (const float*)d_in[11], (const float*)d_in[12], (const float*)d_in[13],
        (const float*)d_in[14], (const float*)d_in[15], (const float*)d_in[16],
        (const float*)d_in[17],
        (const float*)d_in[18], (const float*)d_in[19], (const float*)d_in[20],
        (const float*)d_in[21], (const float*)d_in[22], (const float*)d_in[23],
        (const float*)d_in[24],
        (float*)d_out);
}